// Round 3
// baseline (94.707 us; speedup 1.0000x reference)
//
#include <hip/hip_runtime.h>
#include <stdint.h>

// QTIP hybrid codebook dequant:
//   c    = uint32(code)            (codes are in [0, 65536))
//   t    = (c+1)*c                 (uint32 wraparound exact; only low 16 bits matter)
//   sflp = bit15(t) ? -1 : +1      (applied to component 0 only)
//   idx  = (t >> 6) & 511
//   out[2i+0] = lut[idx].x * sflp
//   out[2i+1] = lut[idx].y
//
// Memory-bound: 128 MiB read + 256 MiB write => ~64 us floor at 6.3 TB/s.

__global__ __launch_bounds__(256) void qtip_lut_kernel(
    const int* __restrict__ codes,
    const float* __restrict__ lut,
    float* __restrict__ out,
    int n)  // number of codes
{
    // Stage the 4 KiB LUT into LDS (512 x float2).
    __shared__ float2 slut[512];
    for (int i = threadIdx.x; i < 512; i += 256)
        slut[i] = reinterpret_cast<const float2*>(lut)[i];
    __syncthreads();

    const int n4 = n >> 2;
    const int stride = gridDim.x * blockDim.x;
    const int tid0 = blockIdx.x * blockDim.x + threadIdx.x;
    const int4* __restrict__ codes4 = reinterpret_cast<const int4*>(codes);
    float4* __restrict__ out4 = reinterpret_cast<float4*>(out);

    for (int i = tid0; i < n4; i += stride) {
        int4 c4 = codes4[i];

        float2 e0, e1, e2, e3;
        {
            uint32_t c = (uint32_t)c4.x;
            uint32_t t = (c + 1u) * c;
            float2 g = slut[(t >> 6) & 511u];
            e0.x = __uint_as_float(__float_as_uint(g.x) ^ ((t << 16) & 0x80000000u));
            e0.y = g.y;
        }
        {
            uint32_t c = (uint32_t)c4.y;
            uint32_t t = (c + 1u) * c;
            float2 g = slut[(t >> 6) & 511u];
            e1.x = __uint_as_float(__float_as_uint(g.x) ^ ((t << 16) & 0x80000000u));
            e1.y = g.y;
        }
        {
            uint32_t c = (uint32_t)c4.z;
            uint32_t t = (c + 1u) * c;
            float2 g = slut[(t >> 6) & 511u];
            e2.x = __uint_as_float(__float_as_uint(g.x) ^ ((t << 16) & 0x80000000u));
            e2.y = g.y;
        }
        {
            uint32_t c = (uint32_t)c4.w;
            uint32_t t = (c + 1u) * c;
            float2 g = slut[(t >> 6) & 511u];
            e3.x = __uint_as_float(__float_as_uint(g.x) ^ ((t << 16) & 0x80000000u));
            e3.y = g.y;
        }

        float4 r0, r1;
        r0.x = e0.x; r0.y = e0.y; r0.z = e1.x; r0.w = e1.y;
        r1.x = e2.x; r1.y = e2.y; r1.z = e3.x; r1.w = e3.y;
        out4[2 * i]     = r0;
        out4[2 * i + 1] = r1;
    }

    // Scalar tail (n % 4 != 0) — not expected for this problem (n = 2^25),
    // but keeps the kernel correct for any size.
    for (int i = (n4 << 2) + tid0; i < n; i += stride) {
        uint32_t c = (uint32_t)codes[i];
        uint32_t t = (c + 1u) * c;
        float2 g = slut[(t >> 6) & 511u];
        out[2 * i]     = __uint_as_float(__float_as_uint(g.x) ^ ((t << 16) & 0x80000000u));
        out[2 * i + 1] = g.y;
    }
}

extern "C" void kernel_launch(void* const* d_in, const int* in_sizes, int n_in,
                              void* d_out, int out_size, void* d_ws, size_t ws_size,
                              hipStream_t stream) {
    const int* codes = (const int*)d_in[0];
    const float* lut = (const float*)d_in[1];
    float* out = (float*)d_out;
    const int n = in_sizes[0];  // 8192*4096 codes

    int n4 = n >> 2;
    int blocks = (n4 + 255) / 256;
    if (blocks > 2048) blocks = 2048;
    if (blocks < 1) blocks = 1;

    qtip_lut_kernel<<<blocks, 256, 0, stream>>>(codes, lut, out, n);
}

// Round 4
// 76.679 us; speedup vs baseline: 1.2351x; 1.2351x over previous
//
#include <hip/hip_runtime.h>
#include <stdint.h>

// QTIP hybrid codebook dequant:
//   c    = uint32(code), c < 2^16
//   t    = (c+1)*c            (only low 16 bits matter; u24 mul exact)
//   sign = bit15(t)           (flips component 0 only)
//   idx  = (t >> 6) & 511
//   out[2i] = lut[idx].x ^sign ; out[2i+1] = lut[idx].y
//
// Memory-bound: 128 MiB read + 256 MiB write => ~60-64 us floor.
// R3 change: 4-deep load unrolling (1 -> 4 outstanding global loads per wave)
// to fix the latency/ILP shortfall diagnosed at 4.25 TB/s effective.

typedef int   v4i __attribute__((ext_vector_type(4)));
typedef float v4f __attribute__((ext_vector_type(4)));

__device__ __forceinline__ float2 qtip_one(const float2* __restrict__ slut, uint32_t c) {
    uint32_t t = __umul24(c + 1u, c);   // exact: both operands < 2^24, low 32b kept
    float2 g = slut[(t >> 6) & 511u];
    float2 r;
    r.x = __uint_as_float(__float_as_uint(g.x) ^ ((t << 16) & 0x80000000u));
    r.y = g.y;
    return r;
}

__device__ __forceinline__ void qtip_proc4(const float2* __restrict__ slut,
                                           v4i c4, v4f* __restrict__ out4, int i) {
    float2 e0 = qtip_one(slut, (uint32_t)c4.x);
    float2 e1 = qtip_one(slut, (uint32_t)c4.y);
    float2 e2 = qtip_one(slut, (uint32_t)c4.z);
    float2 e3 = qtip_one(slut, (uint32_t)c4.w);
    v4f r0 = {e0.x, e0.y, e1.x, e1.y};
    v4f r1 = {e2.x, e2.y, e3.x, e3.y};
    out4[2 * i]     = r0;
    out4[2 * i + 1] = r1;
}

__global__ __launch_bounds__(256, 8) void qtip_lut_kernel(
    const int* __restrict__ codes,
    const float* __restrict__ lut,
    float* __restrict__ out,
    int n)  // number of codes
{
    // Stage the 4 KiB LUT into LDS (512 x float2).
    __shared__ float2 slut[512];
    for (int i = threadIdx.x; i < 512; i += 256)
        slut[i] = reinterpret_cast<const float2*>(lut)[i];
    __syncthreads();

    const int n4 = n >> 2;
    const int stride = gridDim.x * blockDim.x;
    const int tid0 = blockIdx.x * blockDim.x + threadIdx.x;
    const v4i* __restrict__ codes4 = reinterpret_cast<const v4i*>(codes);
    v4f* __restrict__ out4 = reinterpret_cast<v4f*>(out);

    const int iters = n4 / stride;  // uniform across all threads
    int i = tid0;
    int it = 0;

    // Main: 4 independent loads in flight before any use.
    for (; it + 4 <= iters; it += 4) {
        v4i ca = __builtin_nontemporal_load(&codes4[i]);
        v4i cb = __builtin_nontemporal_load(&codes4[i + stride]);
        v4i cc = __builtin_nontemporal_load(&codes4[i + 2 * stride]);
        v4i cd = __builtin_nontemporal_load(&codes4[i + 3 * stride]);
        qtip_proc4(slut, ca, out4, i);
        qtip_proc4(slut, cb, out4, i + stride);
        qtip_proc4(slut, cc, out4, i + 2 * stride);
        qtip_proc4(slut, cd, out4, i + 3 * stride);
        i += 4 * stride;
    }
    // Leftover uniform rounds (iters % 4).
    for (; it < iters; ++it) {
        v4i c4 = __builtin_nontemporal_load(&codes4[i]);
        qtip_proc4(slut, c4, out4, i);
        i += stride;
    }
    // Residual int4s past the uniform region (at most one round, some threads).
    for (int j = iters * stride + tid0; j < n4; j += stride) {
        v4i c4 = __builtin_nontemporal_load(&codes4[j]);
        qtip_proc4(slut, c4, out4, j);
    }
    // Scalar tail (n % 4 != 0) — not hit for this problem (n = 2^25).
    for (int k = (n4 << 2) + tid0; k < n; k += stride) {
        float2 e = qtip_one(slut, (uint32_t)codes[k]);
        out[2 * k]     = e.x;
        out[2 * k + 1] = e.y;
    }
}

extern "C" void kernel_launch(void* const* d_in, const int* in_sizes, int n_in,
                              void* d_out, int out_size, void* d_ws, size_t ws_size,
                              hipStream_t stream) {
    const int* codes = (const int*)d_in[0];
    const float* lut = (const float*)d_in[1];
    float* out = (float*)d_out;
    const int n = in_sizes[0];  // 8192*4096 codes

    int n4 = n >> 2;
    int blocks = (n4 + 255) / 256;
    if (blocks > 2048) blocks = 2048;  // 8 blocks/CU x 256 CUs, 32 waves/CU
    if (blocks < 1) blocks = 1;

    qtip_lut_kernel<<<blocks, 256, 0, stream>>>(codes, lut, out, n);
}